// Round 9
// baseline (145.799 us; speedup 1.0000x reference)
//
#include <hip/hip_runtime.h>
#include <math.h>

#define BQ   8
#define CIN  256
#define HH   64
#define WW   64
#define COUT 256
#define K2   9
#define PCH  27

#define PT     64            // pixels per block (one full row)
#define CCH    32            // channels per chunk
#define NCHUNK (CIN / CCH)   // 8
#define NSTEP  72            // total MFMA K-steps (of 32)
#define NSUB   24            // sub-chunks (3 taps = 3 K-steps each)
#define SUBROW 104           // sub-chunk row stride in shorts (96 + 8 pad)
#define PLANE  (HH * WW)     // 4096

#define NPAR   512                           // param-conv blocks (512 thr)
#define NXT    (BQ * HH * 4)                 // 2048 transpose blocks (512 thr)
#define NPW    ((NSTEP * COUT * 4) / 512)    // 144 packw blocks (512 thr)
#define NPREP  (NPAR + NXT + NPW)            // 2704

typedef __attribute__((ext_vector_type(8))) short short8;
typedef __attribute__((ext_vector_type(4))) float f32x4;
typedef __attribute__((ext_vector_type(2))) float f32x2;

// raw barrier: waits LDS writes, does NOT drain vmcnt (global prefetches
// stay in flight); leading+trailing compiler memory fences pin ordering.
#define PIPE_BARRIER() do {                                   \
    asm volatile("s_waitcnt lgkmcnt(0)" ::: "memory");        \
    __builtin_amdgcn_s_barrier();                             \
    asm volatile("" ::: "memory");                            \
} while (0)

static __device__ __forceinline__ unsigned short f2bf(float f) {
    unsigned u = __builtin_bit_cast(unsigned, f);
    u += 0x7fff + ((u >> 16) & 1);          // round-to-nearest-even
    return (unsigned short)(u >> 16);
}
static __device__ __forceinline__ f32x2 up2(unsigned u) {   // 2 bf16 -> 2 f32
    f32x2 r;
    r[0] = __builtin_bit_cast(float, u << 16);
    r[1] = __builtin_bit_cast(float, u & 0xffff0000u);
    return r;
}
static __device__ __forceinline__ unsigned cvtpk(float lo, float hi) {
    unsigned r;
    asm("v_cvt_pk_bf16_f32 %0, %1, %2" : "=v"(r) : "v"(lo), "v"(hi));
    return r;
}

// ---------------------------------------------------------------------------
// Kernel 1: pack param-gen weight [27][256][9] -> MFMA A-fragments (tiny,
// runs first so the merged prep kernel's param blocks can consume wpg).
// ---------------------------------------------------------------------------
__global__ __launch_bounds__(256) void k_pg(const float* __restrict__ pgw,
                                            unsigned short* __restrict__ wpg) {
    int t = blockIdx.x * 256 + threadIdx.x;       // (s*32 + o)*4 + q
    if (t >= NSTEP * 32 * 4) return;
    int q = t & 3;
    int o = (t >> 2) & 31;
    int s = t >> 7;
    short8 sv;
#pragma unroll
    for (int j = 0; j < 8; ++j) {
        int pos   = s * 32 + q * 8 + j;
        int chunk = pos / (CCH * K2);
        int pl    = pos % (CCH * K2);
        int ktap  = pl >> 5;
        int c     = chunk * CCH + (pl & 31);
        sv[j] = (o < PCH) ? (short)f2bf(pgw[(size_t)(o * CIN + c) * K2 + ktap]) : (short)0;
    }
    *(short8*)(wpg + (size_t)t * 8) = sv;
}

// ---------------------------------------------------------------------------
// Kernel 2 (merged prep, 512 thr):
//   blocks [0,512):       param-generator conv (reads x DIRECTLY in NCHW --
//                         no xT dependency, overlaps the transpose blocks)
//   blocks [512,2560):    xT transpose (NCHW f32 -> NHWC bf16)
//   blocks [2560,2704):   pack main weight
// ---------------------------------------------------------------------------
__global__ __launch_bounds__(512, 2) void k_prep(const float* __restrict__ x,
                                                 unsigned short* __restrict__ xT,
                                                 const float* __restrict__ w,
                                                 unsigned short* __restrict__ wp,
                                                 const unsigned short* __restrict__ wpg,
                                                 const float* __restrict__ pgb,
                                                 float* __restrict__ pv) {
    __shared__ alignas(16) unsigned short smem[2][3][66][40];   // 31,680 B
    int blk = blockIdx.x;
    int tid = threadIdx.x;

    if (blk < NPAR) {
        // ---- param-generator: dense 3x3 conv, 27 outs, from NCHW x ----
        int swz = (blk & 7) * 64 + (blk >> 3);   // XCD-chunked (512 % 8 == 0)
        int b   = swz >> 6;
        int h   = swz & 63;

        int wv  = tid >> 6;
        int lm  = tid & 15;
        int lq  = (tid >> 4) & 3;
        int ipg = wv >> 2;                  // M tile 0..1 (oc 0-15 / 16-31)
        int rpg = wv & 3;                   // pixel tile 0..3

        // zero border columns (px index 0 and 65) in BOTH buffers once
        if (tid < 48) {
            int bufk = tid >= 24;
            int tt  = tid - bufk * 24;
            int ky  = tt >> 3;
            int rem = tt & 7;
            int col = (rem >> 2) * 65;
            int q   = rem & 3;
            uint4 z = make_uint4(0, 0, 0, 0);
            *(uint4*)&smem[bufk][ky][col][q * 8] = z;
        }
        __syncthreads();

        f32x4 accA = (f32x4){0.f, 0.f, 0.f, 0.f};
        f32x4 accB = (f32x4){0.f, 0.f, 0.f, 0.f};

        int cst = tid >> 4;                 // staging channel-in-chunk 0..31
        int px0 = (tid & 15) * 4;           // staging pixel base

        const float* xb = x + (size_t)b * CIN * PLANE;

        // prologue: chunk-0 rows -> registers
        float4 R[3];
#pragma unroll
        for (int ky = 0; ky < 3; ++ky) {
            int y = h + ky - 1;
            R[ky] = make_float4(0.f, 0.f, 0.f, 0.f);
            if ((unsigned)y < (unsigned)HH)
                R[ky] = *(const float4*)(xb + ((size_t)cst * HH + y) * WW + px0);
        }

        for (int ch = 0; ch < NCHUNK; ++ch) {
#pragma unroll
            for (int ky = 0; ky < 3; ++ky) {
                smem[ch & 1][ky][px0 + 1][cst] = f2bf(R[ky].x);
                smem[ch & 1][ky][px0 + 2][cst] = f2bf(R[ky].y);
                smem[ch & 1][ky][px0 + 3][cst] = f2bf(R[ky].z);
                smem[ch & 1][ky][px0 + 4][cst] = f2bf(R[ky].w);
            }
            if (ch + 1 < NCHUNK) {
#pragma unroll
                for (int ky = 0; ky < 3; ++ky) {
                    int y = h + ky - 1;
                    R[ky] = make_float4(0.f, 0.f, 0.f, 0.f);
                    if ((unsigned)y < (unsigned)HH)
                        R[ky] = *(const float4*)(xb + ((size_t)((ch + 1) * CCH + cst) * HH + y) * WW + px0);
                }
            }
            __syncthreads();
#pragma unroll
            for (int tap = 0; tap < K2; ++tap) {
                int ky = tap / 3, kx = tap % 3;
                short8 a  = *(const short8*)(wpg + (size_t)(ch * K2 + tap) * 32 * 32
                                             + (ipg * 16 + lm) * 32 + lq * 8);
                short8 bf = *(const short8*)&smem[ch & 1][ky][rpg * 16 + lm + kx][lq * 8];
                if (tap & 1)
                    accB = __builtin_amdgcn_mfma_f32_16x16x32_bf16(a, bf, accB, 0, 0, 0);
                else
                    accA = __builtin_amdgcn_mfma_f32_16x16x32_bf16(a, bf, accA, 0, 0, 0);
            }
        }

        f32x4 accpg = accA + accB;
        int px = rpg * 16 + lm;
#pragma unroll
        for (int rg = 0; rg < 4; ++rg) {
            int oc = ipg * 16 + lq * 4 + rg;
            if (oc < PCH)
                pv[((size_t)(b * PCH + oc) << 12) + h * WW + px] = accpg[rg] + pgb[oc];
        }
    } else if (blk < NPAR + NXT) {
        // ---- xT repack: NCHW f32 -> xT[b][y*64+x][c] bf16 ----
        float (*tile)[65] = (float (*)[65])&smem[0][0][0][0];   // 16,640 B alias
        int bb  = blk - NPAR;
        int cc  = bb & 3;
        int y   = (bb >> 2) & 63;
        int b   = bb >> 8;
        int c0  = cc * 64;

        const float* xp = x + ((size_t)(b * CIN + c0) * HH + y) * WW;
#pragma unroll
        for (int r = 0; r < 8; ++r) {
            int cl = r * 8 + (tid >> 6);
            int xx = tid & 63;
            tile[cl][xx] = xp[(size_t)cl * PLANE + xx];
        }
        __syncthreads();
        unsigned short* op = xT + ((size_t)b * PLANE + (size_t)y * WW) * CIN + c0;
#pragma unroll
        for (int r = 0; r < 8; ++r) {
            int xx = r * 8 + (tid >> 6);
            int cl = tid & 63;
            op[(size_t)xx * CIN + cl] = f2bf(tile[cl][xx]);
        }
    } else {
        // ---- pack main weight -> MFMA A-fragments ----
        int t = (blk - NPAR - NXT) * 512 + tid;   // (s*256 + o)*4 + q
        int q = t & 3;
        int o = (t >> 2) & 255;
        int s = t >> 10;
        short8 sv;
#pragma unroll
        for (int j = 0; j < 8; ++j) {
            int pos   = s * 32 + q * 8 + j;       // 0..2303
            int chunk = pos / (CCH * K2);
            int pl    = pos % (CCH * K2);
            int ktap  = pl >> 5;
            int c     = chunk * CCH + (pl & 31);
            sv[j] = (short)f2bf(w[(o * CIN + c) * K2 + ktap]);
        }
        *(short8*)(wp + (size_t)t * 8) = sv;
    }
}

// ---------------------------------------------------------------------------
// Fused kernel: tables -> deform-conv GEMM.
// Round 9: R5-corrected wave retiling. Wave owns 64 outs x 32 px:
//   - B-fragment ds_reads per step 4 -> 2 (halves the dominant LDS pipe,
//     measured ~23 us of the 85.5);
//   - ALL 4 A-fragments prefetched one step ahead (R5's missing piece);
//   - gather/combine/staging pipeline + barriers UNTOUCHED (R4-proven).
// ---------------------------------------------------------------------------
__global__ __launch_bounds__(512, 4) void k_fused(const unsigned short* __restrict__ xT,
                                                  const unsigned short* __restrict__ wp,
                                                  const float* __restrict__ pv,
                                                  const float* __restrict__ bias,
                                                  float* __restrict__ out) {
    __shared__ alignas(16) unsigned short s_samp[2][PT][SUBROW]; // 26,624 B
    __shared__ float4 s_wgt4[K2][PT];                            //  9,216 B
    __shared__ int4   s_off4[K2][PT];                            //  9,216 B

    int blk = blockIdx.x;
    int swz = (blk & 7) * 64 + (blk >> 3);   // XCD-chunked (512 % 8 == 0)
    int b   = swz >> 6;
    int h   = swz & 63;
    int t   = threadIdx.x;

    // roles
    int gp = t >> 3;                    // gather pixel 0..63
    int cg = t & 7;                     // 4-channel group 0..7
    int wv = t >> 6;                    // wave 0..7
    int lm = t & 15;
    int lq = (t >> 4) & 3;

    const char* xTb = (const char*)xT + (size_t)b * PLANE * CIN * 2;

    // ================= Phase B: sampling tables =================
    const float* pvb = pv + ((size_t)(b * PCH) << 12) + h * WW;
    for (int e = t; e < K2 * PT; e += 512) {
        int k = e >> 6;
        int p = e & 63;
        float dy = pvb[(size_t)(2 * k) << 12 | (unsigned)p];
        float dx = pvb[(size_t)(2 * k + 1) << 12 | (unsigned)p];
        float mz = pvb[(size_t)(18 + k) << 12 | (unsigned)p];
        float m  = 1.f / (1.f + expf(-mz));

        float py = dy + (float)(h - 1 + k / 3);
        float px = dx + (float)(p - 1 + k % 3);
        float y0f = floorf(py), x0f = floorf(px);
        float fy = py - y0f,    fx = px - x0f;
        int iy0 = (int)y0f, ix0 = (int)x0f;
        int iy1 = iy0 + 1,  ix1 = ix0 + 1;
        bool vy0 = (unsigned)iy0 < (unsigned)HH;
        bool vy1 = (unsigned)iy1 < (unsigned)HH;
        bool vx0 = (unsigned)ix0 < (unsigned)WW;
        bool vx1 = (unsigned)ix1 < (unsigned)WW;

        float w00 = (1.f - fy) * (1.f - fx) * m; if (!(vy0 && vx0)) w00 = 0.f;
        float w01 = (1.f - fy) * fx         * m; if (!(vy0 && vx1)) w01 = 0.f;
        float w10 = fy         * (1.f - fx) * m; if (!(vy1 && vx0)) w10 = 0.f;
        float w11 = fy         * fx         * m; if (!(vy1 && vx1)) w11 = 0.f;

        int cy0 = min(max(iy0, 0), HH - 1), cy1 = min(max(iy1, 0), HH - 1);
        int cx0 = min(max(ix0, 0), WW - 1), cx1 = min(max(ix1, 0), WW - 1);

        s_wgt4[k][p] = make_float4(w00, w01, w10, w11);
        s_off4[k][p] = make_int4((cy0 * WW + cx0) * 512, (cy0 * WW + cx1) * 512,
                                 (cy1 * WW + cx0) * 512, (cy1 * WW + cx1) * 512);
    }
    __syncthreads();

    // ================= Phase C: main deform GEMM (pipelined) =================
    int ow  = (wv >> 1) * 64;           // wave owns 64 outputs
    int pxt = (wv & 1) * 32;            // ... and 32 pixels
    f32x4 acc[4][2];
#pragma unroll
    for (int i = 0; i < 4; ++i)
#pragma unroll
        for (int j = 0; j < 2; ++j) acc[i][j] = (f32x4){0.f, 0.f, 0.f, 0.f};

    uint2 G[3][4];                      // 24 VGPR gather prefetch
    // prologue: gather+combine sub-chunk 0, issue sub-chunk-1 loads
    {
#pragma unroll
        for (int j = 0; j < 3; ++j) {
            int4 ob = s_off4[j][gp];
            G[j][0] = *(const uint2*)(xTb + ob.x + cg * 8);
            G[j][1] = *(const uint2*)(xTb + ob.y + cg * 8);
            G[j][2] = *(const uint2*)(xTb + ob.z + cg * 8);
            G[j][3] = *(const uint2*)(xTb + ob.w + cg * 8);
        }
#pragma unroll
        for (int j = 0; j < 3; ++j) {
            float4 gw = s_wgt4[j][gp];
            f32x2 v01 = gw.x * up2(G[j][0].x) + gw.y * up2(G[j][1].x)
                      + gw.z * up2(G[j][2].x) + gw.w * up2(G[j][3].x);
            f32x2 v23 = gw.x * up2(G[j][0].y) + gw.y * up2(G[j][1].y)
                      + gw.z * up2(G[j][2].y) + gw.w * up2(G[j][3].y);
            uint2 pk;
            pk.x = cvtpk(v01[0], v01[1]);
            pk.y = cvtpk(v23[0], v23[1]);
            *(uint2*)&s_samp[0][gp][j * 32 + cg * 4] = pk;
        }
#pragma unroll
        for (int j = 0; j < 3; ++j) {
            int4 ob = s_off4[3 + j][gp];
            G[j][0] = *(const uint2*)(xTb + ob.x + cg * 8);
            G[j][1] = *(const uint2*)(xTb + ob.y + cg * 8);
            G[j][2] = *(const uint2*)(xTb + ob.z + cg * 8);
            G[j][3] = *(const uint2*)(xTb + ob.w + cg * 8);
        }
        PIPE_BARRIER();
    }

    short8 aC[4], aN[4];
#pragma unroll
    for (int i = 0; i < 4; ++i)
        aC[i] = *(const short8*)(wp + (ow + i * 16 + lm) * 32 + lq * 8);

    for (int sc = 0; sc < NSUB; ++sc) {
        bool doC = (sc + 1 < NSUB);
        bool doL = (sc + 2 < NSUB);
        int t1 = ((sc + 1) % 3) * 3;
        int t2 = ((sc + 2) % 3) * 3;
        int c2 = ((sc + 2) / 3) * (CCH * 2) + cg * 8;
        unsigned short (*__restrict__ bc)[SUBROW] = s_samp[sc & 1];
        unsigned short (*__restrict__ bn)[SUBROW] = s_samp[(sc + 1) & 1];
#pragma unroll
        for (int sl = 0; sl < 3; ++sl) {
            short8 b0 = *(const short8*)&bc[pxt +  0 + lm][sl * 32 + lq * 8];
            short8 b1 = *(const short8*)&bc[pxt + 16 + lm][sl * 32 + lq * 8];
            int r = sc * 3 + sl + 1;
#pragma unroll
            for (int i = 0; i < 4; ++i) aN[i] = aC[i];
            if (r < NSTEP) {
                const unsigned short* wrn = wp + (size_t)r * COUT * 32;
#pragma unroll
                for (int i = 0; i < 4; ++i)
                    aN[i] = *(const short8*)(wrn + (ow + i * 16 + lm) * 32 + lq * 8);
            }
            if (doC) {                  // combine sub-chunk sc+1, tap sl -> bn
                float4 gw = s_wgt4[t1 + sl][gp];
                f32x2 v01 = gw.x * up2(G[sl][0].x) + gw.y * up2(G[sl][1].x)
                          + gw.z * up2(G[sl][2].x) + gw.w * up2(G[sl][3].x);
                f32x2 v23 = gw.x * up2(G[sl][0].y) + gw.y * up2(G[sl][1].y)
                          + gw.z * up2(G[sl][2].y) + gw.w * up2(G[sl][3].y);
                uint2 pk;
                pk.x = cvtpk(v01[0], v01[1]);
                pk.y = cvtpk(v23[0], v23[1]);
                *(uint2*)&bn[gp][sl * 32 + cg * 4] = pk;
            }
            if (doL) {                  // prefetch sub-chunk sc+2, tap sl
                int4 ob = s_off4[t2 + sl][gp];
                G[sl][0] = *(const uint2*)(xTb + ob.x + c2);
                G[sl][1] = *(const uint2*)(xTb + ob.y + c2);
                G[sl][2] = *(const uint2*)(xTb + ob.z + c2);
                G[sl][3] = *(const uint2*)(xTb + ob.w + c2);
            }
            __builtin_amdgcn_s_setprio(1);
            acc[0][0] = __builtin_amdgcn_mfma_f32_16x16x32_bf16(aC[0], b0, acc[0][0], 0, 0, 0);
            acc[0][1] = __builtin_amdgcn_mfma_f32_16x16x32_bf16(aC[0], b1, acc[0][1], 0, 0, 0);
            acc[1][0] = __builtin_amdgcn_mfma_f32_16x16x32_bf16(aC[1], b0, acc[1][0], 0, 0, 0);
            acc[1][1] = __builtin_amdgcn_mfma_f32_16x16x32_bf16(aC[1], b1, acc[1][1], 0, 0, 0);
            acc[2][0] = __builtin_amdgcn_mfma_f32_16x16x32_bf16(aC[2], b0, acc[2][0], 0, 0, 0);
            acc[2][1] = __builtin_amdgcn_mfma_f32_16x16x32_bf16(aC[2], b1, acc[2][1], 0, 0, 0);
            acc[3][0] = __builtin_amdgcn_mfma_f32_16x16x32_bf16(aC[3], b0, acc[3][0], 0, 0, 0);
            acc[3][1] = __builtin_amdgcn_mfma_f32_16x16x32_bf16(aC[3], b1, acc[3][1], 0, 0, 0);
            __builtin_amdgcn_s_setprio(0);
#pragma unroll
            for (int i = 0; i < 4; ++i) aC[i] = aN[i];
        }
        PIPE_BARRIER();
    }

    // ================= epilogue =================
    float* op = out + ((size_t)b * COUT) * PLANE + h * WW + pxt;
#pragma unroll
    for (int i = 0; i < 4; ++i) {
        int o0 = ow + i * 16 + lq * 4;
        f32x4 bv = *(const f32x4*)(bias + o0);
#pragma unroll
        for (int rg = 0; rg < 4; ++rg) {
#pragma unroll
            for (int j = 0; j < 2; ++j)
                op[(size_t)(o0 + rg) * PLANE + j * 16 + lm] = acc[i][j][rg] + bv[rg];
        }
    }
}

// ---------------------------------------------------------------------------
extern "C" void kernel_launch(void* const* d_in, const int* in_sizes, int n_in,
                              void* d_out, int out_size, void* d_ws, size_t ws_size,
                              hipStream_t stream) {
    const float* x    = (const float*)d_in[0];
    const float* wgt  = (const float*)d_in[1];
    const float* bias = (const float*)d_in[2];
    const float* pgw  = (const float*)d_in[3];
    const float* pgb  = (const float*)d_in[4];
    float* out = (float*)d_out;

    const size_t WPK_B = (size_t)NSTEP * COUT * 32 * 2;   //  1,179,648
    const size_t WPG_B = (size_t)NSTEP * 32 * 32 * 2;     //    147,456
    const size_t XT_B  = (size_t)BQ * PLANE * CIN * 2;    // 16,777,216
    unsigned short* wpk = (unsigned short*)d_ws;
    unsigned short* wpg = (unsigned short*)((char*)d_ws + WPK_B);
    unsigned short* xT  = (unsigned short*)((char*)d_ws + WPK_B + WPG_B);
    float*          pv  = (float*)((char*)d_ws + WPK_B + WPG_B + XT_B);  // 3.54 MB

    k_pg   <<<(NSTEP * 32 * 4 + 255) / 256, 256, 0, stream>>>(pgw, wpg);
    k_prep <<<NPREP, 512, 0, stream>>>(x, xT, wgt, wpk, wpg, pgb, pv);
    k_fused<<<BQ * HH, 512, 0, stream>>>(xT, wpk, pv, bias, out);
}

// Round 10
// 104.229 us; speedup vs baseline: 1.3988x; 1.3988x over previous
//
#include <hip/hip_runtime.h>
#include <math.h>

#define BQ   8
#define CIN  256
#define HH   64
#define WW   64
#define COUT 256
#define K2   9
#define PCH  27

#define PT     64            // pixels per block (one full row)
#define CCH    32            // channels per chunk
#define NCHUNK (CIN / CCH)   // 8
#define NSTEP  72            // total MFMA K-steps (of 32)
#define NSUB   24            // sub-chunks (3 taps = 3 K-steps each)
#define SUBROW 104           // sub-chunk row stride in shorts (96 + 8 pad)
#define PLANE  (HH * WW)     // 4096

#define NXT    (BQ * HH * 4)                 // 2048 xt blocks
#define NPW    ((NSTEP * COUT * 4) / 256)    // 288 packw blocks
#define NPG    ((NSTEP * 32 * 4) / 256)      // 36 packpg blocks
#define NPREP  (NXT + NPW + NPG)             // 2372

typedef __attribute__((ext_vector_type(8))) short short8;
typedef __attribute__((ext_vector_type(4))) float f32x4;
typedef __attribute__((ext_vector_type(2))) float f32x2;

// raw barrier: waits LDS writes, does NOT drain vmcnt (global prefetches
// stay in flight); leading+trailing compiler memory fences pin ordering.
#define PIPE_BARRIER() do {                                   \
    asm volatile("s_waitcnt lgkmcnt(0)" ::: "memory");        \
    __builtin_amdgcn_s_barrier();                             \
    asm volatile("" ::: "memory");                            \
} while (0)

static __device__ __forceinline__ unsigned short f2bf(float f) {
    unsigned u = __builtin_bit_cast(unsigned, f);
    u += 0x7fff + ((u >> 16) & 1);          // round-to-nearest-even
    return (unsigned short)(u >> 16);
}
static __device__ __forceinline__ f32x2 up2(unsigned u) {   // 2 bf16 -> 2 f32
    f32x2 r;
    r[0] = __builtin_bit_cast(float, u << 16);
    r[1] = __builtin_bit_cast(float, u & 0xffff0000u);
    return r;
}
static __device__ __forceinline__ unsigned cvtpk(float lo, float hi) {
    unsigned r;
    asm("v_cvt_pk_bf16_f32 %0, %1, %2" : "=v"(r) : "v"(lo), "v"(hi));
    return r;
}

// ---------------------------------------------------------------------------
// Merged prep kernel: [0,2048) xT transpose; [2048,2336) packw; [2336,2372) packpg.
// (R8-proven version, unchanged.)
// ---------------------------------------------------------------------------
__global__ __launch_bounds__(256) void k_prep(const float* __restrict__ x,
                                              unsigned short* __restrict__ xT,
                                              const float* __restrict__ w,
                                              unsigned short* __restrict__ wp,
                                              const float* __restrict__ pgw,
                                              unsigned short* __restrict__ wpg) {
    __shared__ float tile[64][65];
    int blk = blockIdx.x;

    if (blk < NXT) {
        // ---- xT repack: NCHW f32 -> xT[b][y*64+x][c] bf16 ----
        int cc  = blk & 3;
        int y   = (blk >> 2) & 63;
        int b   = blk >> 8;
        int t   = threadIdx.x;
        int c0  = cc * 64;

        const float* xp = x + ((size_t)(b * CIN + c0) * HH + y) * WW;
#pragma unroll
        for (int r = 0; r < 16; ++r) {
            int cl = r * 4 + (t >> 6);
            int xx = t & 63;
            tile[cl][xx] = xp[(size_t)cl * PLANE + xx];
        }
        __syncthreads();
        unsigned short* op = xT + ((size_t)b * PLANE + (size_t)y * WW) * CIN + c0;
#pragma unroll
        for (int r = 0; r < 16; ++r) {
            int xx = r * 4 + (t >> 6);
            int cl = t & 63;
            op[(size_t)xx * CIN + cl] = f2bf(tile[cl][xx]);
        }
    } else if (blk < NXT + NPW) {
        // ---- pack main weight -> MFMA A-fragments ----
        int t = (blk - NXT) * 256 + threadIdx.x;    // (s*256 + o)*4 + q
        int q = t & 3;
        int o = (t >> 2) & 255;
        int s = t >> 10;
        short8 sv;
#pragma unroll
        for (int j = 0; j < 8; ++j) {
            int pos   = s * 32 + q * 8 + j;         // 0..2303
            int chunk = pos / (CCH * K2);
            int pl    = pos % (CCH * K2);
            int ktap  = pl >> 5;
            int c     = chunk * CCH + (pl & 31);
            sv[j] = (short)f2bf(w[(o * CIN + c) * K2 + ktap]);
        }
        *(short8*)(wp + (size_t)t * 8) = sv;
    } else {
        // ---- pack param-gen weight (32 rows: 27 real + 5 zero) ----
        int t = (blk - NXT - NPW) * 256 + threadIdx.x;   // (s*32 + o)*4 + q
        int q = t & 3;
        int o = (t >> 2) & 31;
        int s = t >> 7;
        short8 sv;
#pragma unroll
        for (int j = 0; j < 8; ++j) {
            int pos   = s * 32 + q * 8 + j;
            int chunk = pos / (CCH * K2);
            int pl    = pos % (CCH * K2);
            int ktap  = pl >> 5;
            int c     = chunk * CCH + (pl & 31);
            sv[j] = (o < PCH) ? (short)f2bf(pgw[(size_t)(o * CIN + c) * K2 + ktap]) : (short)0;
        }
        *(short8*)(wpg + (size_t)t * 8) = sv;
    }
}

// ---------------------------------------------------------------------------
// Kernel 0d: standalone param-generator (dense 3x3 conv, 27 outs).
// Round 10: 2-ROW tiling. Block computes output rows h0,h0+1 (M=32 oc x
// N=128 = 2x64 px) from 4 staged input rows -> xT re-read factor 3x -> 2x
// (50 -> 33.5 MB HBM). Grid 256 = exactly 1 block/CU. Same R8-proven
// dbuf + 1-sync-per-chunk pipeline. LDS 42.2 KB.
// ---------------------------------------------------------------------------
__global__ __launch_bounds__(512, 2) void k_params(const unsigned short* __restrict__ xT,
                                                   const unsigned short* __restrict__ wpg,
                                                   const float* __restrict__ pgb,
                                                   float* __restrict__ pv) {
    __shared__ alignas(16) unsigned short s_rows[2][4][66][40];   // 42,240 B

    int blk = blockIdx.x;
    int swz = (blk & 7) * 32 + (blk >> 3);   // XCD-chunked (256 % 8 == 0)
    int b   = swz >> 5;
    int h0  = (swz & 31) * 2;
    int t   = threadIdx.x;

    int wv  = t >> 6;
    int lm  = t & 15;
    int lq  = (t >> 4) & 3;
    int ipg = wv >> 2;                  // oc tile 0..1 (oc 0-15 / 16-31)
    int seg = wv & 3;                   // n-segment 0..3 (32 cols each)
    int ryb = seg >> 1;                 // output-row within pair
    int pxb = (seg & 1) * 32;           // px base within row

    const unsigned short* xTb = xT + (size_t)b * PLANE * CIN;

    // zero border columns (array px 0 and 65) in both buffers, all 4 rows
    if (t < 64) {
        int buf = t >> 5;
        int ry  = (t >> 3) & 3;
        int col = ((t >> 2) & 1) * 65;
        int q   = t & 3;
        uint4 z = make_uint4(0, 0, 0, 0);
        *(uint4*)&s_rows[buf][ry][col][q * 8] = z;
    }
    __syncthreads();

    f32x4 acc0 = (f32x4){0.f, 0.f, 0.f, 0.f};
    f32x4 acc1 = (f32x4){0.f, 0.f, 0.f, 0.f};

    int pxm1 = t >> 3;                  // 0..63 (staging pixel)
    int cgs  = (t & 7) * 4;             // short offset within 32-ch chunk

    // prologue: load chunk-0 rows into registers
    uint2 R[4];
#pragma unroll
    for (int ry = 0; ry < 4; ++ry) {
        int y = h0 + ry - 1;
        R[ry] = make_uint2(0, 0);
        if ((unsigned)y < (unsigned)HH)
            R[ry] = *(const uint2*)(xTb + (size_t)(y * WW + pxm1) * CIN + cgs);
    }

    for (int ch = 0; ch < NCHUNK; ++ch) {
        // write staged rows of chunk ch; issue chunk ch+1 loads
#pragma unroll
        for (int ry = 0; ry < 4; ++ry)
            *(uint2*)&s_rows[ch & 1][ry][pxm1 + 1][cgs] = R[ry];
        if (ch + 1 < NCHUNK) {
#pragma unroll
            for (int ry = 0; ry < 4; ++ry) {
                int y = h0 + ry - 1;
                R[ry] = make_uint2(0, 0);
                if ((unsigned)y < (unsigned)HH)
                    R[ry] = *(const uint2*)(xTb + (size_t)(y * WW + pxm1) * CIN
                                            + (ch + 1) * CCH + cgs);
            }
        }
        __syncthreads();
#pragma unroll
        for (int tap = 0; tap < K2; ++tap) {
            int ky = tap / 3, kx = tap % 3;
            short8 a  = *(const short8*)(wpg + (size_t)(ch * K2 + tap) * 32 * 32
                                         + (ipg * 16 + lm) * 32 + lq * 8);
            short8 bf0 = *(const short8*)&s_rows[ch & 1][ryb + ky][pxb +  0 + lm + kx][lq * 8];
            short8 bf1 = *(const short8*)&s_rows[ch & 1][ryb + ky][pxb + 16 + lm + kx][lq * 8];
            acc0 = __builtin_amdgcn_mfma_f32_16x16x32_bf16(a, bf0, acc0, 0, 0, 0);
            acc1 = __builtin_amdgcn_mfma_f32_16x16x32_bf16(a, bf1, acc1, 0, 0, 0);
        }
    }

    float* pvo = pv + ((size_t)(b * PCH) << 12) + (h0 + ryb) * WW;
#pragma unroll
    for (int rg = 0; rg < 4; ++rg) {
        int oc = ipg * 16 + lq * 4 + rg;
        if (oc < PCH) {
            float bb = pgb[oc];
            pvo[((size_t)oc << 12) + pxb +  0 + lm] = acc0[rg] + bb;
            pvo[((size_t)oc << 12) + pxb + 16 + lm] = acc1[rg] + bb;
        }
    }
}

// ---------------------------------------------------------------------------
// Fused kernel: tables (from global params) -> deform-conv GEMM.
// Round 10: EXACT R8 version (proven 85.5 us) minus s_setprio (m190: setprio
// hurts barrier-locked GEMM convoys). No other change.
// ---------------------------------------------------------------------------
__global__ __launch_bounds__(512, 4) void k_fused(const unsigned short* __restrict__ xT,
                                                  const unsigned short* __restrict__ wp,
                                                  const float* __restrict__ pv,
                                                  const float* __restrict__ bias,
                                                  float* __restrict__ out) {
    __shared__ alignas(16) unsigned short s_samp[2][PT][SUBROW]; // 26,624 B
    __shared__ float4 s_wgt4[K2][PT];                            //  9,216 B
    __shared__ int4   s_off4[K2][PT];                            //  9,216 B

    int blk = blockIdx.x;
    int swz = (blk & 7) * 64 + (blk >> 3);   // XCD-chunked (512 % 8 == 0)
    int b   = swz >> 6;
    int h   = swz & 63;
    int t   = threadIdx.x;

    // roles
    int gp = t >> 3;                    // gather pixel 0..63
    int cg = t & 7;                     // 4-channel group 0..7
    int wv = t >> 6;                    // wave 0..7
    int lm = t & 15;
    int lq = (t >> 4) & 3;

    const char* xTb = (const char*)xT + (size_t)b * PLANE * CIN * 2;

    // ================= Phase B: sampling tables =================
    const float* pvb = pv + ((size_t)(b * PCH) << 12) + h * WW;
    for (int e = t; e < K2 * PT; e += 512) {
        int k = e >> 6;
        int p = e & 63;
        float dy = pvb[(size_t)(2 * k) << 12 | (unsigned)p];
        float dx = pvb[(size_t)(2 * k + 1) << 12 | (unsigned)p];
        float mz = pvb[(size_t)(18 + k) << 12 | (unsigned)p];
        float m  = 1.f / (1.f + expf(-mz));

        float py = dy + (float)(h - 1 + k / 3);
        float px = dx + (float)(p - 1 + k % 3);
        float y0f = floorf(py), x0f = floorf(px);
        float fy = py - y0f,    fx = px - x0f;
        int iy0 = (int)y0f, ix0 = (int)x0f;
        int iy1 = iy0 + 1,  ix1 = ix0 + 1;
        bool vy0 = (unsigned)iy0 < (unsigned)HH;
        bool vy1 = (unsigned)iy1 < (unsigned)HH;
        bool vx0 = (unsigned)ix0 < (unsigned)WW;
        bool vx1 = (unsigned)ix1 < (unsigned)WW;

        float w00 = (1.f - fy) * (1.f - fx) * m; if (!(vy0 && vx0)) w00 = 0.f;
        float w01 = (1.f - fy) * fx         * m; if (!(vy0 && vx1)) w01 = 0.f;
        float w10 = fy         * (1.f - fx) * m; if (!(vy1 && vx0)) w10 = 0.f;
        float w11 = fy         * fx         * m; if (!(vy1 && vx1)) w11 = 0.f;

        int cy0 = min(max(iy0, 0), HH - 1), cy1 = min(max(iy1, 0), HH - 1);
        int cx0 = min(max(ix0, 0), WW - 1), cx1 = min(max(ix1, 0), WW - 1);

        s_wgt4[k][p] = make_float4(w00, w01, w10, w11);
        s_off4[k][p] = make_int4((cy0 * WW + cx0) * 512, (cy0 * WW + cx1) * 512,
                                 (cy1 * WW + cx0) * 512, (cy1 * WW + cx1) * 512);
    }
    __syncthreads();

    // ================= Phase C: main deform GEMM (pipelined) =================
    int ow = wv * 32;                   // o base: wave owns 32 outputs
    f32x4 acc[2][4];
#pragma unroll
    for (int i = 0; i < 2; ++i)
#pragma unroll
        for (int j = 0; j < 4; ++j) acc[i][j] = (f32x4){0.f, 0.f, 0.f, 0.f};

    uint2 G[3][4];                      // 24 VGPR gather prefetch
    // prologue: gather+combine sub-chunk 0, issue sub-chunk-1 loads
    {
#pragma unroll
        for (int j = 0; j < 3; ++j) {
            int4 ob = s_off4[j][gp];
            G[j][0] = *(const uint2*)(xTb + ob.x + cg * 8);
            G[j][1] = *(const uint2*)(xTb + ob.y + cg * 8);
            G[j][2] = *(const uint2*)(xTb + ob.z + cg * 8);
            G[j][3] = *(const uint2*)(xTb + ob.w + cg * 8);
        }
#pragma unroll
        for (int j = 0; j < 3; ++j) {
            float4 gw = s_wgt4[j][gp];
            f32x2 v01 = gw.x * up2(G[j][0].x) + gw.y * up2(G[j][1].x)
                      + gw.z * up2(G[j][2].x) + gw.w * up2(G[j][3].x);
            f32x2 v23 = gw.x * up2(G[j][0].y) + gw.y * up2(G[j][1].y)
                      + gw.z * up2(G[j][2].y) + gw.w * up2(G[j][3].y);
            uint2 pk;
            pk.x = cvtpk(v01[0], v01[1]);
            pk.y = cvtpk(v23[0], v23[1]);
            *(uint2*)&s_samp[0][gp][j * 32 + cg * 4] = pk;
        }
#pragma unroll
        for (int j = 0; j < 3; ++j) {
            int4 ob = s_off4[3 + j][gp];
            G[j][0] = *(const uint2*)(xTb + ob.x + cg * 8);
            G[j][1] = *(const uint2*)(xTb + ob.y + cg * 8);
            G[j][2] = *(const uint2*)(xTb + ob.z + cg * 8);
            G[j][3] = *(const uint2*)(xTb + ob.w + cg * 8);
        }
        PIPE_BARRIER();
    }

    short8 a0c = *(const short8*)(wp + (ow +  0 + lm) * 32 + lq * 8);
    short8 a1c = *(const short8*)(wp + (ow + 16 + lm) * 32 + lq * 8);
    for (int sc = 0; sc < NSUB; ++sc) {
        bool doC = (sc + 1 < NSUB);
        bool doL = (sc + 2 < NSUB);
        int t1 = ((sc + 1) % 3) * 3;
        int t2 = ((sc + 2) % 3) * 3;
        int c2 = ((sc + 2) / 3) * (CCH * 2) + cg * 8;
        unsigned short (*__restrict__ bc)[SUBROW] = s_samp[sc & 1];
        unsigned short (*__restrict__ bn)[SUBROW] = s_samp[(sc + 1) & 1];
#pragma unroll
        for (int sl = 0; sl < 3; ++sl) {
            short8 b0 = *(const short8*)&bc[ 0 + lm][sl * 32 + lq * 8];
            short8 b1 = *(const short8*)&bc[16 + lm][sl * 32 + lq * 8];
            short8 b2 = *(const short8*)&bc[32 + lm][sl * 32 + lq * 8];
            short8 b3 = *(const short8*)&bc[48 + lm][sl * 32 + lq * 8];
            int r = sc * 3 + sl + 1;
            short8 a0n = a0c, a1n = a1c;
            if (r < NSTEP) {
                const unsigned short* wrn = wp + (size_t)r * COUT * 32;
                a0n = *(const short8*)(wrn + (ow +  0 + lm) * 32 + lq * 8);
                a1n = *(const short8*)(wrn + (ow + 16 + lm) * 32 + lq * 8);
            }
            if (doC) {                  // combine sub-chunk sc+1, tap sl -> bn
                float4 gw = s_wgt4[t1 + sl][gp];
                f32x2 v01 = gw.x * up2(G[sl][0].x) + gw.y * up2(G[sl][1].x)
                          + gw.z * up2(G[sl][2].x) + gw.w * up2(G[sl][3].x);
                f32x2 v23 = gw.x * up2(G[sl][0].y) + gw.y * up2(G[sl][1].y)
                          + gw.z * up2(G[sl][2].y) + gw.w * up2(G[sl][3].y);
                uint2 pk;
                pk.x = cvtpk(v01[0], v01[1]);
                pk.y = cvtpk(v23[0], v23[1]);
                *(uint2*)&bn[gp][sl * 32 + cg * 4] = pk;
            }
            if (doL) {                  // prefetch sub-chunk sc+2, tap sl
                int4 ob = s_off4[t2 + sl][gp];
                G[sl][0] = *(const uint2*)(xTb + ob.x + c2);
                G[sl][1] = *(const uint2*)(xTb + ob.y + c2);
                G[sl][2] = *(const uint2*)(xTb + ob.z + c2);
                G[sl][3] = *(const uint2*)(xTb + ob.w + c2);
            }
            acc[0][0] = __builtin_amdgcn_mfma_f32_16x16x32_bf16(a0c, b0, acc[0][0], 0, 0, 0);
            acc[0][1] = __builtin_amdgcn_mfma_f32_16x16x32_bf16(a0c, b1, acc[0][1], 0, 0, 0);
            acc[0][2] = __builtin_amdgcn_mfma_f32_16x16x32_bf16(a0c, b2, acc[0][2], 0, 0, 0);
            acc[0][3] = __builtin_amdgcn_mfma_f32_16x16x32_bf16(a0c, b3, acc[0][3], 0, 0, 0);
            acc[1][0] = __builtin_amdgcn_mfma_f32_16x16x32_bf16(a1c, b0, acc[1][0], 0, 0, 0);
            acc[1][1] = __builtin_amdgcn_mfma_f32_16x16x32_bf16(a1c, b1, acc[1][1], 0, 0, 0);
            acc[1][2] = __builtin_amdgcn_mfma_f32_16x16x32_bf16(a1c, b2, acc[1][2], 0, 0, 0);
            acc[1][3] = __builtin_amdgcn_mfma_f32_16x16x32_bf16(a1c, b3, acc[1][3], 0, 0, 0);
            a0c = a0n; a1c = a1n;
        }
        PIPE_BARRIER();
    }

    // ================= epilogue =================
    float* op = out + ((size_t)b * COUT) * PLANE + h * WW;
#pragma unroll
    for (int i = 0; i < 2; ++i) {
        int o0 = ow + i * 16 + lq * 4;
        f32x4 bv = *(const f32x4*)(bias + o0);
#pragma unroll
        for (int rg = 0; rg < 4; ++rg) {
#pragma unroll
            for (int j = 0; j < 4; ++j)
                op[(size_t)(o0 + rg) * PLANE + j * 16 + lm] = acc[i][j][rg] + bv[rg];
        }
    }
}

// ---------------------------------------------------------------------------
extern "C" void kernel_launch(void* const* d_in, const int* in_sizes, int n_in,
                              void* d_out, int out_size, void* d_ws, size_t ws_size,
                              hipStream_t stream) {
    const float* x    = (const float*)d_in[0];
    const float* wgt  = (const float*)d_in[1];
    const float* bias = (const float*)d_in[2];
    const float* pgw  = (const float*)d_in[3];
    const float* pgb  = (const float*)d_in[4];
    float* out = (float*)d_out;

    const size_t WPK_B = (size_t)NSTEP * COUT * 32 * 2;   //  1,179,648
    const size_t WPG_B = (size_t)NSTEP * 32 * 32 * 2;     //    147,456
    const size_t XT_B  = (size_t)BQ * PLANE * CIN * 2;    // 16,777,216
    unsigned short* wpk = (unsigned short*)d_ws;
    unsigned short* wpg = (unsigned short*)((char*)d_ws + WPK_B);
    unsigned short* xT  = (unsigned short*)((char*)d_ws + WPK_B + WPG_B);
    float*          pv  = (float*)((char*)d_ws + WPK_B + WPG_B + XT_B);  // 3.54 MB

    k_prep  <<<NPREP, 256, 0, stream>>>(x, xT, wgt, wpk, pgw, wpg);
    k_params<<<BQ * HH / 2, 512, 0, stream>>>(xT, wpg, pgb, pv);
    k_fused <<<BQ * HH, 512, 0, stream>>>(xT, wpk, pv, bias, out);
}